// Round 3
// baseline (746.049 us; speedup 1.0000x reference)
//
#include <hip/hip_runtime.h>
#include <math.h>

using f4 = __attribute__((ext_vector_type(4))) float;

#define NS 64
#define NI 32
#define NK 16

// ws layout (floats)
#define OFF_D   0                    // 16*64
#define OFF_WTZ 1024                 // 16*32*32, [k][i][o]
#define OFF_WTY (1024 + 16384)
#define OFF_WTX (1024 + 2*16384)
#define OFF_W0T (1024 + 3*16384)     // 64*32, w0t[j][i] = w0[i][j]
#define WS_FLOATS (1024 + 3*16384 + 2048)   // 52224

__device__ inline float dot4(f4 a, f4 b) { f4 p = a * b; return p[0] + p[1] + p[2] + p[3]; }

__global__ __launch_bounds__(256) void init_kernel(
    const float* __restrict__ fw_x, const float* __restrict__ fw_y,
    const float* __restrict__ fw_z, const float* __restrict__ w0,
    float* __restrict__ ws)
{
    int gid = blockIdx.x * 256 + threadIdx.x;
    if (gid < 1024) {
        // D[k][n] = s_k * cos(pi * k * (2n+1) / 128), orthonormal DCT-II
        int k = gid >> 6, n = gid & 63;
        float s = (k == 0) ? 0.125f : sqrtf(2.0f / 64.0f);
        ws[OFF_D + gid] = s * cospif((float)((2 * n + 1) * k) / 128.0f);
    } else if (gid < 1024 + 3 * 16384) {
        int r = gid - 1024;
        int a = r / 16384;           // 0:z 1:y 2:x
        int q = r % 16384;           // q = k*1024 + i*32 + o
        int k = q >> 10;
        int i = (q >> 5) & 31;
        int o = q & 31;
        const float* fw = (a == 0) ? fw_z : (a == 1) ? fw_y : fw_x;  // fw[(i*32+o)*16+k]
        ws[1024 + a * 16384 + q] = fw[(i * 32 + o) * 16 + k];
    } else if (gid < WS_FLOATS) {
        int r = gid - (1024 + 3 * 16384);  // r = j*32 + i
        int j = r >> 5, i = r & 31;
        ws[OFF_W0T + r] = w0[i * 64 + j];
    }
}

// One block = 4 slabs (64 positions x 32 channels each) along AXIS.
// h_slab = D^T @ mix_k( D_trunc @ X_slab ).
// MODE: 0 = write h, 1 = accumulate into h, 2 = accumulate + fused FF + final write.
template<int AXIS, int MODE>
__global__ __launch_bounds__(256) void axis_kernel(
    const float* __restrict__ x, float* __restrict__ h,
    const float* __restrict__ ws, const float* __restrict__ w1g,
    const float* __restrict__ b0g, const float* __restrict__ b1g)
{
    __shared__ f4 Xl[2048];    // 8192 floats: AXIS2: [s][m][i]; else [m][s][i]; later reused as Hl
    __shared__ f4 Ul[512];     // U[s][k][i]  (s*512 + k*32 + i floats)
    __shared__ f4 Vl[512];     // V[s][k][o]
    __shared__ float Dl[1024]; // D[k][n]

    const int t = threadIdx.x;
    const int bid = blockIdx.x;            // 4096 blocks = 4 * 64 * 16
    const int b  = bid >> 10;
    const int c1 = (bid >> 4) & 63;
    const int c2 = bid & 15;               // slab group of 4

    const float* Dg = ws + OFF_D;
    const float* Wt = ws + (AXIS == 2 ? OFF_WTZ : AXIS == 1 ? OFF_WTY : OFF_WTX);

    int base, strideM, strideS;
    if (AXIS == 2) { base = ((b * 64 + c1) * 64 + c2 * 4) * 2048;      strideM = 32;     strideS = 2048; }
    if (AXIS == 1) { base = (b * 64 + c1) * 131072 + c2 * 128;         strideM = 2048;   strideS = 32; }
    if (AXIS == 0) { base = b * 8388608 + c1 * 2048 + c2 * 128;        strideM = 131072; strideS = 32; }

    #pragma unroll
    for (int q = 0; q < 4; ++q) Dl[t + 256 * q] = Dg[t + 256 * q];

    const f4* xg = reinterpret_cast<const f4*>(x);
    if (AXIS == 2) {
        int b4 = base >> 2;   // tile is fully contiguous
        #pragma unroll
        for (int q = 0; q < 8; ++q) Xl[t + 256 * q] = xg[b4 + t + 256 * q];
    } else {
        #pragma unroll
        for (int q = 0; q < 8; ++q) {
            int j = t + 256 * q;          // 0..2047
            int m = j >> 5, c = j & 31;   // per-m chunk: 128 contiguous floats [s][i]
            Xl[j] = xg[((base + m * strideM) >> 2) + c];
        }
    }
    __syncthreads();

    // Phase 1: U[s][k][i] = sum_m D[k][m] * X[s][m][i]
    #pragma unroll
    for (int it = 0; it < 2; ++it) {
        int id = t + 256 * it;             // (s,k,i4): 4*16*8 = 512
        int i4 = id & 7, k = (id >> 3) & 15, s = id >> 7;
        f4 acc = {0.f, 0.f, 0.f, 0.f};
        #pragma unroll
        for (int m = 0; m < 64; ++m) {
            f4 xv = Xl[AXIS == 2 ? (s * 512 + m * 8 + i4) : (m * 32 + s * 8 + i4)];
            acc += xv * Dl[k * 64 + m];
        }
        Ul[s * 128 + k * 8 + i4] = acc;
    }
    __syncthreads();

    // Phase 2: V[s][k][o] = sum_i U[s][k][i] * Wt[k][i][o]   (128 threads)
    if (t < 128) {
        int k = t >> 3, o4 = t & 7;
        const f4* Wt4 = reinterpret_cast<const f4*>(Wt);
        const float* Us = reinterpret_cast<const float*>(Ul);
        f4 v0 = {0.f,0.f,0.f,0.f}, v1 = v0, v2 = v0, v3 = v0;
        #pragma unroll 8
        for (int i = 0; i < 32; ++i) {
            f4 w = Wt4[k * 256 + i * 8 + o4];
            v0 += w * Us[0 * 512 + k * 32 + i];
            v1 += w * Us[1 * 512 + k * 32 + i];
            v2 += w * Us[2 * 512 + k * 32 + i];
            v3 += w * Us[3 * 512 + k * 32 + i];
        }
        Vl[0 * 128 + k * 8 + o4] = v0;
        Vl[1 * 128 + k * 8 + o4] = v1;
        Vl[2 * 128 + k * 8 + o4] = v2;
        Vl[3 * 128 + k * 8 + o4] = v3;
    }
    __syncthreads();

    // Phase 3: acc[s][n][o] = sum_k D[k][n] * V[s][k][o]  (+ prior h for MODE>=1)
    f4* hg = reinterpret_cast<f4*>(h);
    #pragma unroll
    for (int it = 0; it < 8; ++it) {
        int id = t + 256 * it;             // (s,n,o4): 4*64*8 = 2048
        int o4 = id & 7, n = (id >> 3) & 63, s = id >> 9;
        f4 acc = {0.f, 0.f, 0.f, 0.f};
        #pragma unroll
        for (int k = 0; k < 16; ++k)
            acc += Vl[s * 128 + k * 8 + o4] * Dl[k * 64 + n];
        int hi4 = ((base + n * strideM + s * strideS) >> 2) + o4;
        if constexpr (MODE == 2) {
            // h_final staged to LDS (reuse Xl), XOR-swizzled for bank-uniform access
            acc += hg[hi4];
            Xl[(s * 64 + n) * 8 + (o4 ^ (n & 7))] = acc;
        } else {
            if (MODE == 1) acc += hg[hi4];
            hg[hi4] = acc;
        }
    }

    if constexpr (MODE == 2) {
        // Fused FeedForward: out = relu(h@w0+b0)@w1 + b1, one position per thread.
        __shared__ f4 w0s[512];   // w0t[j][i4]
        __shared__ f4 w1s[512];   // w1[j][o4]
        __shared__ float b0s[64];
        __shared__ f4 b1s[8];
        const f4* w0t4 = reinterpret_cast<const f4*>(ws + OFF_W0T);
        const f4* w14  = reinterpret_cast<const f4*>(w1g);
        w0s[t] = w0t4[t];  w0s[t + 256] = w0t4[t + 256];
        w1s[t] = w14[t];   w1s[t + 256] = w14[t + 256];
        if (t < 64) b0s[t] = b0g[t];
        if (t < 8)  b1s[t] = reinterpret_cast<const f4*>(b1g)[t];
        __syncthreads();   // Hl stores + weight loads visible

        {
            int n = t & 63, sw = n & 7;
            f4 h0[8], a0[8];
            #pragma unroll
            for (int q = 0; q < 8; ++q) {
                h0[q] = Xl[t * 8 + (q ^ sw)];
                a0[q] = b1s[q];
            }
            #pragma unroll 8
            for (int j = 0; j < 64; ++j) {
                float s0 = b0s[j];
                #pragma unroll
                for (int q = 0; q < 8; ++q) s0 += dot4(h0[q], w0s[j * 8 + q]);
                s0 = fmaxf(s0, 0.f);
                #pragma unroll
                for (int q = 0; q < 8; ++q) a0[q] += w1s[j * 8 + q] * s0;
            }
            // each thread owns its 32 floats exclusively: no barrier needed
            #pragma unroll
            for (int q = 0; q < 8; ++q) Xl[t * 8 + (q ^ sw)] = a0[q];
        }
        __syncthreads();

        // cooperative final write, 8-lane x 128B merged pattern
        #pragma unroll
        for (int it = 0; it < 8; ++it) {
            int id = t + 256 * it;
            int o4 = id & 7, n = (id >> 3) & 63, s = id >> 9;
            f4 v = Xl[(s * 64 + n) * 8 + (o4 ^ (n & 7))];
            hg[((base + n * strideM + s * strideS) >> 2) + o4] = v;
        }
    }
}

extern "C" void kernel_launch(void* const* d_in, const int* in_sizes, int n_in,
                              void* d_out, int out_size, void* d_ws, size_t ws_size,
                              hipStream_t stream)
{
    const float* x   = (const float*)d_in[0];
    const float* fwx = (const float*)d_in[1];
    const float* fwy = (const float*)d_in[2];
    const float* fwz = (const float*)d_in[3];
    const float* w0  = (const float*)d_in[4];
    const float* b0  = (const float*)d_in[5];
    const float* w1  = (const float*)d_in[6];
    const float* b1  = (const float*)d_in[7];
    float* out = (float*)d_out;
    float* ws  = (float*)d_ws;

    if (ws_size < WS_FLOATS * sizeof(float)) return;

    init_kernel<<<(WS_FLOATS + 255) / 256, 256, 0, stream>>>(fwx, fwy, fwz, w0, ws);
    // h accumulates in d_out (same shape/layout as output)
    axis_kernel<2, 0><<<4096, 256, 0, stream>>>(x, out, ws, w1, b0, b1);
    axis_kernel<1, 1><<<4096, 256, 0, stream>>>(x, out, ws, w1, b0, b1);
    axis_kernel<0, 2><<<4096, 256, 0, stream>>>(x, out, ws, w1, b0, b1);  // + fused FF
}